// Round 6
// baseline (3746.671 us; speedup 1.0000x reference)
//
#include <hip/hip_runtime.h>
#include <cmath>

typedef _Float16 half8  __attribute__((ext_vector_type(8)));
typedef _Float16 half4v __attribute__((ext_vector_type(4)));
typedef float    float4v __attribute__((ext_vector_type(4)));

// ---------------------------------------------------------------------------
// MFMA conv3x3 (SAME), fp16 in / fp32 acc / fp16 out (relu).
// WG = 256 thr = 4 waves stacked on px (144 px each); wave co = MT*16.
// A (weights) via LDS in read-order (conflict-free). B (pixels) from global.
// MODE 0: patch conv reading the padded IMAGE directly; per-lane zero masks
//         emulate the per-patch SAME padding (kills the g_patch/P1 copy).
// MODE 1: patch conv from padded per-patch buffer [NB][26][26][CI] (ring=0).
// MODE 2: image conv from padded image [b][RSI][RSI][CI]; batch in px_b>>6.
// launch_bounds (256,2): 256-VGPR budget. (256,4) spilled accs (R3, 14x).
// XCD swizzle (R5): id = xcd + 8*(group*NC + co_t) keeps all co-tiles of one
// px-block on one XCD -> activation slab stays in that XCD's L2.
// ---------------------------------------------------------------------------
template<int MT, int MODE, int CI, int RSI, int RSO>
__global__ __launch_bounds__(256, 2)
void mfma_conv(const _Float16* __restrict__ in, const _Float16* __restrict__ Wg,
               const float* __restrict__ bias, _Float16* __restrict__ out,
               int CO, int NB, int NC, int p0)
{
    __shared__ __align__(16) _Float16 sW[9 * MT * 64 * 8];

    const int tid  = threadIdx.x;
    const int wave = tid >> 6;
    const int lane = tid & 63;
    const int ll   = lane & 15;
    const int quad = lane >> 4;

    const int id   = blockIdx.x;
    const int xcd  = id & 7;
    const int slot = id >> 3;
    const int px_b = (slot / NC) * 8 + xcd;
    const int co_t = slot % NC;
    if (px_b >= NB) return;
    const int co0 = co_t * (MT * 16);

    size_t in_base, out_base;
    int ty = 0, tx = 0, pi = 0, pj = 0;
    if (MODE == 0) {
        int pat = p0 + px_b;
        int bb = pat / 225; int rem = pat % 225; pi = rem / 15; pj = rem % 15;
        in_base  = (size_t)bb * RSI * RSI * CI;
        out_base = (size_t)px_b * 676 * CO;
    } else if (MODE == 1) {
        in_base  = (size_t)px_b * 676 * CI;
        out_base = (size_t)px_b * 676 * CO;
    } else {
        int tile = px_b & 63, bb = px_b >> 6;
        ty = tile >> 3; tx = tile & 7;
        in_base  = (size_t)bb * RSI * RSI * CI;
        out_base = (size_t)bb * RSO * RSO * CO;
    }

    int b_off[9];
    int edge[9];
    #pragma unroll
    for (int nt = 0; nt < 9; ++nt) {
        int p = wave * 144 + nt * 16 + ll;
        int py = p / 24, px = p % 24;
        if (MODE == 0) {
            b_off[nt] = ((pi * 12 + py) * RSI + (pj * 12 + px)) * CI;
            edge[nt] = (py == 0 ? 1 : 0) | (py == 23 ? 2 : 0)
                     | (px == 0 ? 4 : 0) | (px == 23 ? 8 : 0);
        } else if (MODE == 1) {
            b_off[nt] = (py * RSI + px) * CI;
        } else {
            b_off[nt] = ((ty * 24 + py) * RSI + (tx * 24 + px)) * CI;
        }
    }

    float4v acc[MT][9];
    #pragma unroll
    for (int mt = 0; mt < MT; ++mt)
        #pragma unroll
        for (int nt = 0; nt < 9; ++nt)
            acc[mt][nt] = (float4v){0.f, 0.f, 0.f, 0.f};

    for (int ci0 = 0; ci0 < CI; ci0 += 32) {
        __syncthreads();
        for (int c = tid; c < 9 * MT * 64; c += 256) {
            int lane_s = c & 63;
            int mtt = c >> 6;
            int mt = mtt % MT, t = mtt / MT;
            *(uint4*)&sW[(size_t)c * 8] =
                *(const uint4*)&Wg[((size_t)(co0 + mt * 16 + (lane_s & 15)) * 9 + t) * CI
                                   + ci0 + (lane_s >> 4) * 8];
        }
        __syncthreads();

        const _Float16* inp = in + in_base + ci0 + quad * 8;
        #pragma unroll
        for (int dy = 0; dy < 3; ++dy) {
            #pragma unroll
            for (int dx = 0; dx < 3; ++dx) {
                const int t = dy * 3 + dx;
                const int toff = (dy * RSI + dx) * CI;
                const int emask = (dy == 0 ? 1 : 0) | (dy == 2 ? 2 : 0)
                                | (dx == 0 ? 4 : 0) | (dx == 2 ? 8 : 0);
                half8 a[MT];
                #pragma unroll
                for (int mt = 0; mt < MT; ++mt)
                    a[mt] = *(const half8*)&sW[((t * MT + mt) * 64 + lane) * 8];
                #pragma unroll
                for (int nt = 0; nt < 9; ++nt) {
                    uint4 raw = *(const uint4*)(inp + b_off[nt] + toff);
                    if (MODE == 0) {
                        bool z = (edge[nt] & emask) != 0;
                        raw.x = z ? 0u : raw.x;
                        raw.y = z ? 0u : raw.y;
                        raw.z = z ? 0u : raw.z;
                        raw.w = z ? 0u : raw.w;
                    }
                    half8 b = *(half8*)&raw;
                    #pragma unroll
                    for (int mt = 0; mt < MT; ++mt)
                        acc[mt][nt] = __builtin_amdgcn_mfma_f32_16x16x32_f16(
                            a[mt], b, acc[mt][nt], 0, 0, 0);
                }
            }
        }
    }

    // epilogue: bias + relu -> fp16; D layout col=lane&15 (px), row=quad*4+reg
    #pragma unroll
    for (int mt = 0; mt < MT; ++mt) {
        float4v bs = *(const float4v*)&bias[co0 + mt * 16 + quad * 4];
        #pragma unroll
        for (int nt = 0; nt < 9; ++nt) {
            int p = wave * 144 + nt * 16 + ll;
            int oy = p / 24 + 1, ox = p % 24 + 1;
            if (MODE == 2) { oy += ty * 24; ox += tx * 24; }
            size_t ooff = out_base + (size_t)(oy * RSO + ox) * CO + co0 + mt * 16 + quad * 4;
            float4v v = acc[mt][nt];
            half4v h;
            h.x = (_Float16)fmaxf(v.x + bs.x, 0.f);
            h.y = (_Float16)fmaxf(v.y + bs.y, 0.f);
            h.z = (_Float16)fmaxf(v.z + bs.z, 0.f);
            h.w = (_Float16)fmaxf(v.w + bs.w, 0.f);
            *(half4v*)(out + ooff) = h;
        }
    }
}

static inline int swiz_grid(int NB, int NC) { return ((NB + 7) & ~7) * NC; }

// ---------------------------------------------------------------------------
// M=1 conv3 as MFMA with CO padded to 16 (rows 1..15 zero weights).
// MODE 1: patch buffer in [NB][26][26][CI]; ACT 1: sigmoid -> outp[blk*576+p]
// MODE 2: image in [b][RSI][RSI][CI];       ACT 2: tanh    -> outp[b*36864+y*192+x]
// ---------------------------------------------------------------------------
template<int MODE, int ACT, int CI, int RSI>
__global__ __launch_bounds__(256, 2)
void mfma_score(const _Float16* __restrict__ in, const _Float16* __restrict__ W16,
                const float* __restrict__ bias, float* __restrict__ outp, int NB)
{
    __shared__ __align__(16) _Float16 sW[9 * 16 * 32];

    const int tid  = threadIdx.x;
    const int wave = tid >> 6;
    const int lane = tid & 63;
    const int ll   = lane & 15;
    const int quad = lane >> 4;

    const int blk = blockIdx.x;
    if (blk >= NB) return;

    size_t in_base;
    int ty = 0, tx = 0, bb = 0;
    if (MODE == 2) {
        bb = blk >> 6; int tile = blk & 63; ty = tile >> 3; tx = tile & 7;
        in_base = (size_t)bb * RSI * RSI * CI;
    } else {
        in_base = (size_t)blk * 676 * CI;
    }

    int b_off[9];
    #pragma unroll
    for (int nt = 0; nt < 9; ++nt) {
        int p = wave * 144 + nt * 16 + ll;
        int py = p / 24, px = p % 24;
        b_off[nt] = (MODE == 2) ? ((ty * 24 + py) * RSI + (tx * 24 + px)) * CI
                                : (py * RSI + px) * CI;
    }

    float4v acc[9];
    #pragma unroll
    for (int nt = 0; nt < 9; ++nt) acc[nt] = (float4v){0.f, 0.f, 0.f, 0.f};

    for (int ci0 = 0; ci0 < CI; ci0 += 32) {
        __syncthreads();
        for (int c = tid; c < 9 * 16 * 4; c += 256) {
            int q = c & 3, tco = c >> 2;
            int t = tco >> 4, co = tco & 15;
            *(uint4*)&sW[tco * 32 + q * 8] =
                *(const uint4*)&W16[((size_t)co * 9 + t) * CI + ci0 + q * 8];
        }
        __syncthreads();

        const _Float16* inp = in + in_base + ci0 + quad * 8;
        #pragma unroll
        for (int dy = 0; dy < 3; ++dy)
            #pragma unroll
            for (int dx = 0; dx < 3; ++dx) {
                const int t = dy * 3 + dx;
                const int toff = (dy * RSI + dx) * CI;
                half8 a = *(const half8*)&sW[(t * 16 + ll) * 32 + quad * 8];
                #pragma unroll
                for (int nt = 0; nt < 9; ++nt) {
                    half8 b = *(const half8*)(inp + b_off[nt] + toff);
                    acc[nt] = __builtin_amdgcn_mfma_f32_16x16x32_f16(a, b, acc[nt], 0, 0, 0);
                }
            }
    }

    if (quad == 0) {
        float bv = bias[0];
        #pragma unroll
        for (int nt = 0; nt < 9; ++nt) {
            int p = wave * 144 + nt * 16 + ll;
            float v = acc[nt].x + bv;          // row co=0 (quad=0, reg=0)
            if (ACT == 1) {
                outp[(size_t)blk * 576 + p] = 1.f / (1.f + expf(-v));
            } else {
                int y = ty * 24 + p / 24, x = tx * 24 + p % 24;
                outp[(size_t)bb * 36864 + y * 192 + x] = tanhf(v);
            }
        }
    }
}

// ---------------------------------------------------------------------------
// helpers
// ---------------------------------------------------------------------------
__global__ __launch_bounds__(256)
void build_x16i(const float* __restrict__ src, const float* __restrict__ tgt,
                _Float16* __restrict__ X)
{
    int idx = blockIdx.x * 256 + threadIdx.x;
    int q = idx & 15, pid = idx >> 4;
    if (pid >= 2 * 36864) return;
    int b = pid / 36864, r = pid % 36864;
    int y = r / 192, x = r % 192;
    half8 h;
    #pragma unroll
    for (int j = 0; j < 8; ++j) {
        int ch = q * 8 + j;
        const float* im = (ch < 64) ? src : tgt;
        h[j] = (_Float16)im[(size_t)(b * 64 + (ch & 63)) * 36864 + r];
    }
    *(half8*)&X[(((size_t)b * 194 + y + 1) * 194 + (x + 1)) * 128 + q * 8] = h;
}

// fp32 OIHW -> fp16 [co][tap][ci]
__global__ __launch_bounds__(256)
void cvt_w(const float* __restrict__ src, _Float16* __restrict__ dst, int CO, int CI)
{
    int idx = blockIdx.x * 256 + threadIdx.x;
    if (idx >= CO * 9 * CI) return;
    int ci = idx % CI, t = (idx / CI) % 9, co = idx / (9 * CI);
    dst[idx] = (_Float16)src[((size_t)co * CI + ci) * 9 + t];
}

// fp32 [1][CI][3][3] -> fp16 [16][tap][ci], rows 1..15 zero
__global__ __launch_bounds__(256)
void cvt_pad16(const float* __restrict__ src, _Float16* __restrict__ dst, int CI)
{
    int idx = blockIdx.x * 256 + threadIdx.x;
    if (idx >= 16 * 9 * CI) return;
    int ci = idx % CI, t = (idx / CI) % 9, co = idx / (9 * CI);
    dst[idx] = (co == 0) ? (_Float16)src[(size_t)ci * 9 + t] : (_Float16)0.0f;
}

// zero the guard ring of a padded NHWC buffer [npatch][RS][RS][CI]
__global__ __launch_bounds__(256)
void ring_zero(_Float16* __restrict__ buf, int npatch, int RS, int CI)
{
    int c8 = CI >> 3;
    int RC = 2 * RS + 2 * (RS - 2);
    int idx = blockIdx.x * 256 + threadIdx.x;
    if (idx >= npatch * RC * c8) return;
    int q = idx % c8, rp = (idx / c8) % RC, pl = idx / (c8 * RC);
    int r, c;
    if (rp < RS)            { r = 0;      c = rp; }
    else if (rp < 2 * RS)   { r = RS - 1; c = rp - RS; }
    else {
        int s = rp - 2 * RS, half = RS - 2;
        if (s < half) { r = s + 1;        c = 0; }
        else          { r = s - half + 1; c = RS - 1; }
    }
    uint4 z = {0u, 0u, 0u, 0u};
    *(uint4*)&buf[((size_t)pl * RS * RS + r * RS + c) * CI + q * 8] = z;
}

// overlap-add normalize (coverage closed-form)
__global__ __launch_bounds__(256)
void att_finalize(const float* __restrict__ score, float* __restrict__ out)
{
    int idx = blockIdx.x * 256 + threadIdx.x;
    if (idx >= 2 * 36864) return;
    int b = idx / 36864, r = idx % 36864;
    int y = r / 192, x = r % 192;
    int i_lo = (y >= 24) ? (y - 12) / 12 : 0;
    int i_hi = min(14, y / 12);
    int j_lo = (x >= 24) ? (x - 12) / 12 : 0;
    int j_hi = min(14, x / 12);
    float s = 0.f; int cnt = 0;
    for (int i = i_lo; i <= i_hi; ++i)
        for (int j = j_lo; j <= j_hi; ++j) {
            s += score[(((size_t)b * 15 + i) * 15 + j) * 576 + (y - 12 * i) * 24 + (x - 12 * j)];
            ++cnt;
        }
    out[idx] = s / (float)cnt;
}

// ---------------------------------------------------------------------------
extern "C" void kernel_launch(void* const* d_in, const int* in_sizes, int n_in,
                              void* d_out, int out_size, void* d_ws, size_t ws_size,
                              hipStream_t stream)
{
    const float* src = (const float*)d_in[0];
    const float* tgt = (const float*)d_in[1];
    const float* W1  = (const float*)d_in[2];  const float* b1  = (const float*)d_in[3];
    const float* W2  = (const float*)d_in[4];  const float* b2  = (const float*)d_in[5];
    const float* W3  = (const float*)d_in[6];  const float* b3  = (const float*)d_in[7];
    const float* Wr1 = (const float*)d_in[8];  const float* br1 = (const float*)d_in[9];
    const float* Wr2 = (const float*)d_in[10]; const float* br2 = (const float*)d_in[11];
    const float* Wr3 = (const float*)d_in[12]; const float* br3 = (const float*)d_in[13];
    float* out = (float*)d_out;

    // ---- fixed workspace (halves) ----
    _Float16* ws = (_Float16*)d_ws;
    size_t o = 0;
    _Float16* X16i = ws + o; o += (size_t)2 * 194 * 194 * 128;
    _Float16* W1h  = ws + o; o += (size_t)512 * 9 * 128;
    _Float16* W2h  = ws + o; o += (size_t)256 * 9 * 512;
    _Float16* Wr1h = ws + o; o += (size_t)512 * 9 * 128;
    _Float16* Wr2h = ws + o; o += (size_t)64 * 9 * 512;
    _Float16* W3p  = ws + o; o += (size_t)16 * 9 * 256;
    _Float16* Wr3p = ws + o; o += (size_t)16 * 9 * 64;
    float*    score = (float*)(ws + o); o += 2 * 259200;
    const size_t fixed_h = o;

    // ---- adaptive patch chunking (no P1 buffer anymore) ----
    const size_t per_patch_h = (size_t)676 * (512 + 256);        // 519,168
    const size_t reg_h = (size_t)2 * 194 * 194 * (512 + 64);     // 43,352,832
    size_t h_avail = ws_size / 2;
    int P = 50;
    {
        size_t n450 = 450 * per_patch_h; if (n450 < reg_h) n450 = reg_h;
        size_t n150 = 150 * per_patch_h; if (n150 < reg_h) n150 = reg_h;
        if (h_avail >= fixed_h + n450)      P = 450;
        else if (h_avail >= fixed_h + n150) P = 150;
    }
    const int nchunks = 450 / P;

    _Float16* D1 = ws + fixed_h;
    _Float16* D2 = D1 + (size_t)P * 676 * 512;
    _Float16* A1 = ws + fixed_h;                                 // region reuse
    _Float16* A2 = A1 + (size_t)2 * 194 * 194 * 512;

    // ---- precompute fp16 operands ----
    ring_zero<<<(2 * 772 * 16 + 255) / 256, 256, 0, stream>>>(X16i, 2, 194, 128);
    build_x16i<<<4608, 256, 0, stream>>>(src, tgt, X16i);
    cvt_w<<<2304, 256, 0, stream>>>(W1,  W1h,  512, 128);
    cvt_w<<<4608, 256, 0, stream>>>(W2,  W2h,  256, 512);
    cvt_w<<<2304, 256, 0, stream>>>(Wr1, Wr1h, 512, 128);
    cvt_w<<<1152, 256, 0, stream>>>(Wr2, Wr2h, 64,  512);
    cvt_pad16<<<(16 * 9 * 256 + 255) / 256, 256, 0, stream>>>(W3,  W3p,  256);
    cvt_pad16<<<(16 * 9 * 64  + 255) / 256, 256, 0, stream>>>(Wr3, Wr3p, 64);

    // ---- attention path ----
    ring_zero<<<(P * 100 * 64 + 255) / 256, 256, 0, stream>>>(D1, P, 26, 512);
    ring_zero<<<(P * 100 * 32 + 255) / 256, 256, 0, stream>>>(D2, P, 26, 256);
    for (int c = 0; c < nchunks; ++c) {
        int p0 = c * P;
        mfma_conv<4, 0, 128, 194, 26><<<swiz_grid(P, 8), 256, 0, stream>>>(
            X16i, W1h, b1, D1, 512, P, 8, p0);
        mfma_conv<4, 1, 512, 26, 26><<<swiz_grid(P, 4), 256, 0, stream>>>(
            D1, W2h, b2, D2, 256, P, 4, 0);
        mfma_score<1, 1, 256, 26><<<P, 256, 0, stream>>>(
            D2, W3p, b3, score + (size_t)p0 * 576, P);
    }
    att_finalize<<<288, 256, 0, stream>>>(score, out + 73728);

    // ---- registration path (batch folded; region reused after attention) ----
    ring_zero<<<(2 * 772 * 64 + 255) / 256, 256, 0, stream>>>(A1, 2, 194, 512);
    ring_zero<<<(2 * 772 * 8  + 255) / 256, 256, 0, stream>>>(A2, 2, 194, 64);
    mfma_conv<4, 2, 128, 194, 194><<<swiz_grid(128, 8), 256, 0, stream>>>(
        X16i, Wr1h, br1, A1, 512, 128, 8, 0);
    mfma_conv<2, 2, 512, 194, 194><<<swiz_grid(128, 2), 256, 0, stream>>>(
        A1, Wr2h, br2, A2, 64, 128, 2, 0);
    mfma_score<2, 2, 64, 194><<<128, 256, 0, stream>>>(A2, Wr3p, br3, out, 128);
}

// Round 7
// 3156.290 us; speedup vs baseline: 1.1870x; 1.1870x over previous
//
#include <hip/hip_runtime.h>
#include <cmath>

typedef _Float16 half8  __attribute__((ext_vector_type(8)));
typedef _Float16 half4v __attribute__((ext_vector_type(4)));
typedef float    float4v __attribute__((ext_vector_type(4)));

// ---------------------------------------------------------------------------
// MFMA conv3x3 (SAME), fp16 in / fp32 acc / fp16 out (relu).
// EXACT R5 kernel (runtime CI/RS: keeps arch VGPR at 108; templating CI in R6
// unrolled the ci-loop, VGPR 128, +23% on conv2 — do not template dims).
// WG = 4 waves; wave tile = (MT*16) co x 144 px. A (weights) via LDS in
// read-order (conflict-free). B (pixels) direct from global.
// launch_bounds (256,2): (256,4) spilled accs (R3, 14x regression).
// XCD swizzle: id = xcd + 8*(group*NC + co_t) -> all co-tiles of one px-block
// on one XCD; px-block activation slab stays in that XCD's L2 (R5: conv2
// FETCH 1.77GB -> 69MB).
// ---------------------------------------------------------------------------
template<int MT>
__global__ __launch_bounds__(256, 2)
void mfma_conv(const _Float16* __restrict__ in, const _Float16* __restrict__ Wg,
               const float* __restrict__ bias, _Float16* __restrict__ out,
               int CI, int CO, int RSin, int RSout, int IMG, int NB, int NC)
{
    __shared__ __align__(16) _Float16 sW[9 * MT * 64 * 8];

    const int tid  = threadIdx.x;
    const int wave = tid >> 6;
    const int lane = tid & 63;
    const int ll   = lane & 15;
    const int quad = lane >> 4;

    const int id   = blockIdx.x;
    const int xcd  = id & 7;
    const int slot = id >> 3;
    const int px_b = (slot / NC) * 8 + xcd;
    const int co_t = slot % NC;
    if (px_b >= NB) return;
    const int co0 = co_t * (MT * 16);

    size_t in_base, out_base;
    if (IMG) {
        int tile = px_b & 63, b = px_b >> 6;
        int ty = tile >> 3, tx = tile & 7;
        in_base  = (size_t)b * RSin * RSin * CI   + (size_t)(ty * 24 * RSin  + tx * 24) * CI;
        out_base = (size_t)b * RSout * RSout * CO + (size_t)(ty * 24 * RSout + tx * 24) * CO;
    } else {
        in_base  = (size_t)px_b * 676 * CI;
        out_base = (size_t)px_b * 676 * CO;
    }

    int b_off[9];
    #pragma unroll
    for (int nt = 0; nt < 9; ++nt) {
        int p = wave * 144 + nt * 16 + ll;
        b_off[nt] = (p / 24) * RSin * CI + (p % 24) * CI;
    }
    int tapoff[9];
    #pragma unroll
    for (int dy = 0; dy < 3; ++dy)
        #pragma unroll
        for (int dx = 0; dx < 3; ++dx)
            tapoff[dy * 3 + dx] = (dy * RSin + dx) * CI;

    float4v acc[MT][9];
    #pragma unroll
    for (int mt = 0; mt < MT; ++mt)
        #pragma unroll
        for (int nt = 0; nt < 9; ++nt)
            acc[mt][nt] = (float4v){0.f, 0.f, 0.f, 0.f};

    for (int ci0 = 0; ci0 < CI; ci0 += 32) {
        __syncthreads();
        for (int c = tid; c < 9 * MT * 64; c += 256) {
            int lane_s = c & 63;
            int mtt = c >> 6;
            int mt = mtt % MT, t = mtt / MT;
            *(uint4*)&sW[(size_t)c * 8] =
                *(const uint4*)&Wg[((size_t)(co0 + mt * 16 + (lane_s & 15)) * 9 + t) * CI
                                   + ci0 + (lane_s >> 4) * 8];
        }
        __syncthreads();

        const _Float16* inp = in + in_base + ci0 + quad * 8;
        #pragma unroll
        for (int t = 0; t < 9; ++t) {
            half8 a[MT];
            #pragma unroll
            for (int mt = 0; mt < MT; ++mt)
                a[mt] = *(const half8*)&sW[((t * MT + mt) * 64 + lane) * 8];
            const int toff = tapoff[t];
            #pragma unroll
            for (int nt = 0; nt < 9; ++nt) {
                half8 b = *(const half8*)(inp + b_off[nt] + toff);
                #pragma unroll
                for (int mt = 0; mt < MT; ++mt)
                    acc[mt][nt] = __builtin_amdgcn_mfma_f32_16x16x32_f16(
                        a[mt], b, acc[mt][nt], 0, 0, 0);
            }
        }
    }

    #pragma unroll
    for (int mt = 0; mt < MT; ++mt) {
        float4v bs = *(const float4v*)&bias[co0 + mt * 16 + quad * 4];
        #pragma unroll
        for (int nt = 0; nt < 9; ++nt) {
            int p = wave * 144 + nt * 16 + ll;
            size_t ooff = out_base
                + (size_t)((p / 24 + 1) * RSout + (p % 24) + 1) * CO
                + co0 + mt * 16 + quad * 4;
            float4v v = acc[mt][nt];
            half4v h;
            h.x = (_Float16)fmaxf(v.x + bs.x, 0.f);
            h.y = (_Float16)fmaxf(v.y + bs.y, 0.f);
            h.z = (_Float16)fmaxf(v.z + bs.z, 0.f);
            h.w = (_Float16)fmaxf(v.w + bs.w, 0.f);
            *(half4v*)(out + ooff) = h;
        }
    }
}

static inline int swiz_grid(int NB, int NC) { return ((NB + 7) & ~7) * NC; }

// ---------------------------------------------------------------------------
// M=1 conv3 via MFMA, CO padded to 16 (rows 1..15 zero). Runtime CI/RSI.
// MODE 1: patch buffer [NB][26][26][CI]; ACT 1: sigmoid -> outp[blk*576+p]
// MODE 2: image [b][RSI][RSI][CI];       ACT 2: tanh    -> outp[b*36864+...]
// Replaces the scalar conv3 kernels (per-lane 512B-stride loads).
// ---------------------------------------------------------------------------
template<int MODE, int ACT>
__global__ __launch_bounds__(256, 2)
void mfma_score(const _Float16* __restrict__ in, const _Float16* __restrict__ W16,
                const float* __restrict__ bias, float* __restrict__ outp,
                int CI, int RSI, int NB)
{
    __shared__ __align__(16) _Float16 sW[9 * 16 * 32];

    const int tid  = threadIdx.x;
    const int wave = tid >> 6;
    const int lane = tid & 63;
    const int ll   = lane & 15;
    const int quad = lane >> 4;

    const int blk = blockIdx.x;
    if (blk >= NB) return;

    size_t in_base;
    int ty = 0, tx = 0, bb = 0;
    if (MODE == 2) {
        bb = blk >> 6; int tile = blk & 63; ty = tile >> 3; tx = tile & 7;
        in_base = (size_t)bb * RSI * RSI * CI;
    } else {
        in_base = (size_t)blk * 676 * CI;
    }

    int b_off[9];
    #pragma unroll
    for (int nt = 0; nt < 9; ++nt) {
        int p = wave * 144 + nt * 16 + ll;
        int py = p / 24, px = p % 24;
        b_off[nt] = (MODE == 2) ? ((ty * 24 + py) * RSI + (tx * 24 + px)) * CI
                                : (py * RSI + px) * CI;
    }

    float4v acc[9];
    #pragma unroll
    for (int nt = 0; nt < 9; ++nt) acc[nt] = (float4v){0.f, 0.f, 0.f, 0.f};

    for (int ci0 = 0; ci0 < CI; ci0 += 32) {
        __syncthreads();
        for (int c = tid; c < 9 * 16 * 4; c += 256) {
            int q = c & 3, tco = c >> 2;
            int t = tco >> 4, co = tco & 15;
            *(uint4*)&sW[tco * 32 + q * 8] =
                *(const uint4*)&W16[((size_t)co * 9 + t) * CI + ci0 + q * 8];
        }
        __syncthreads();

        const _Float16* inp = in + in_base + ci0 + quad * 8;
        for (int dy = 0; dy < 3; ++dy)
            for (int dx = 0; dx < 3; ++dx) {
                const int t = dy * 3 + dx;
                const int toff = (dy * RSI + dx) * CI;
                half8 a = *(const half8*)&sW[(t * 16 + ll) * 32 + quad * 8];
                #pragma unroll
                for (int nt = 0; nt < 9; ++nt) {
                    half8 b = *(const half8*)(inp + b_off[nt] + toff);
                    acc[nt] = __builtin_amdgcn_mfma_f32_16x16x32_f16(a, b, acc[nt], 0, 0, 0);
                }
            }
    }

    if (quad == 0) {
        float bv = bias[0];
        #pragma unroll
        for (int nt = 0; nt < 9; ++nt) {
            int p = wave * 144 + nt * 16 + ll;
            float v = acc[nt].x + bv;          // co=0 row lives in quad 0, reg 0
            if (ACT == 1) {
                outp[(size_t)blk * 576 + p] = 1.f / (1.f + expf(-v));
            } else {
                int y = ty * 24 + p / 24, x = tx * 24 + p % 24;
                outp[(size_t)bb * 36864 + y * 192 + x] = tanhf(v);
            }
        }
    }
}

// ---------------------------------------------------------------------------
// helpers
// ---------------------------------------------------------------------------
__global__ __launch_bounds__(256)
void build_x16i(const float* __restrict__ src, const float* __restrict__ tgt,
                _Float16* __restrict__ X)
{
    int idx = blockIdx.x * 256 + threadIdx.x;
    int q = idx & 15, pid = idx >> 4;
    if (pid >= 2 * 36864) return;
    int b = pid / 36864, r = pid % 36864;
    int y = r / 192, x = r % 192;
    half8 h;
    #pragma unroll
    for (int j = 0; j < 8; ++j) {
        int ch = q * 8 + j;
        const float* im = (ch < 64) ? src : tgt;
        h[j] = (_Float16)im[(size_t)(b * 64 + (ch & 63)) * 36864 + r];
    }
    *(half8*)&X[(((size_t)b * 194 + y + 1) * 194 + (x + 1)) * 128 + q * 8] = h;
}

__global__ __launch_bounds__(256)
void cvt_w(const float* __restrict__ src, _Float16* __restrict__ dst, int CO, int CI)
{
    int idx = blockIdx.x * 256 + threadIdx.x;
    if (idx >= CO * 9 * CI) return;
    int ci = idx % CI, t = (idx / CI) % 9, co = idx / (9 * CI);
    dst[idx] = (_Float16)src[((size_t)co * CI + ci) * 9 + t];
}

// fp32 [1][CI][3][3] -> fp16 [16][tap][ci], rows 1..15 zero
__global__ __launch_bounds__(256)
void cvt_pad16(const float* __restrict__ src, _Float16* __restrict__ dst, int CI)
{
    int idx = blockIdx.x * 256 + threadIdx.x;
    if (idx >= 16 * 9 * CI) return;
    int ci = idx % CI, t = (idx / CI) % 9, co = idx / (9 * CI);
    dst[idx] = (co == 0) ? (_Float16)src[(size_t)ci * 9 + t] : (_Float16)0.0f;
}

__global__ __launch_bounds__(256)
void g_patch(const _Float16* __restrict__ X, _Float16* __restrict__ P1, int p0, int nP)
{
    int idx = blockIdx.x * 256 + threadIdx.x;
    if (idx >= nP * 676 * 16) return;
    int q = idx & 15, t2 = idx >> 4;
    int r676 = t2 % 676, pl = t2 / 676;
    int pr = r676 / 26, pc = r676 % 26;
    int P = p0 + pl;
    int b = P / 225, rem = P % 225, pi = rem / 15, pj = rem % 15;
    uint4 v = {0u, 0u, 0u, 0u};
    if (pr >= 1 && pr <= 24 && pc >= 1 && pc <= 24)
        v = *(const uint4*)&X[(((size_t)b * 194 + pi * 12 + pr) * 194 + (pj * 12 + pc)) * 128 + q * 8];
    *(uint4*)&P1[((size_t)pl * 676 + r676) * 128 + q * 8] = v;
}

__global__ __launch_bounds__(256)
void ring_zero(_Float16* __restrict__ buf, int npatch, int RS, int CI)
{
    int c8 = CI >> 3;
    int RC = 2 * RS + 2 * (RS - 2);
    int idx = blockIdx.x * 256 + threadIdx.x;
    if (idx >= npatch * RC * c8) return;
    int q = idx % c8, rp = (idx / c8) % RC, pl = idx / (c8 * RC);
    int r, c;
    if (rp < RS)            { r = 0;      c = rp; }
    else if (rp < 2 * RS)   { r = RS - 1; c = rp - RS; }
    else {
        int s = rp - 2 * RS, half = RS - 2;
        if (s < half) { r = s + 1;        c = 0; }
        else          { r = s - half + 1; c = RS - 1; }
    }
    uint4 z = {0u, 0u, 0u, 0u};
    *(uint4*)&buf[((size_t)pl * RS * RS + r * RS + c) * CI + q * 8] = z;
}

__global__ __launch_bounds__(256)
void att_finalize(const float* __restrict__ score, float* __restrict__ out)
{
    int idx = blockIdx.x * 256 + threadIdx.x;
    if (idx >= 2 * 36864) return;
    int b = idx / 36864, r = idx % 36864;
    int y = r / 192, x = r % 192;
    int i_lo = (y >= 24) ? (y - 12) / 12 : 0;
    int i_hi = min(14, y / 12);
    int j_lo = (x >= 24) ? (x - 12) / 12 : 0;
    int j_hi = min(14, x / 12);
    float s = 0.f; int cnt = 0;
    for (int i = i_lo; i <= i_hi; ++i)
        for (int j = j_lo; j <= j_hi; ++j) {
            s += score[(((size_t)b * 15 + i) * 15 + j) * 576 + (y - 12 * i) * 24 + (x - 12 * j)];
            ++cnt;
        }
    out[idx] = s / (float)cnt;
}

// ---------------------------------------------------------------------------
extern "C" void kernel_launch(void* const* d_in, const int* in_sizes, int n_in,
                              void* d_out, int out_size, void* d_ws, size_t ws_size,
                              hipStream_t stream)
{
    const float* src = (const float*)d_in[0];
    const float* tgt = (const float*)d_in[1];
    const float* W1  = (const float*)d_in[2];  const float* b1  = (const float*)d_in[3];
    const float* W2  = (const float*)d_in[4];  const float* b2  = (const float*)d_in[5];
    const float* W3  = (const float*)d_in[6];  const float* b3  = (const float*)d_in[7];
    const float* Wr1 = (const float*)d_in[8];  const float* br1 = (const float*)d_in[9];
    const float* Wr2 = (const float*)d_in[10]; const float* br2 = (const float*)d_in[11];
    const float* Wr3 = (const float*)d_in[12]; const float* br3 = (const float*)d_in[13];
    float* out = (float*)d_out;

    // ---- fixed workspace (halves) ----
    _Float16* ws = (_Float16*)d_ws;
    size_t o = 0;
    _Float16* X16i = ws + o; o += (size_t)2 * 194 * 194 * 128;
    _Float16* W1h  = ws + o; o += (size_t)512 * 9 * 128;
    _Float16* W2h  = ws + o; o += (size_t)256 * 9 * 512;
    _Float16* Wr1h = ws + o; o += (size_t)512 * 9 * 128;
    _Float16* Wr2h = ws + o; o += (size_t)64 * 9 * 512;
    _Float16* W3p  = ws + o; o += (size_t)16 * 9 * 256;
    _Float16* Wr3p = ws + o; o += (size_t)16 * 9 * 64;
    float*    score = (float*)(ws + o); o += 2 * 259200;
    const size_t fixed_h = o;

    // ---- adaptive patch chunking (P1 restored) ----
    const size_t per_patch_h = (size_t)676 * (128 + 512 + 256);  // 605,696
    const size_t reg_h = (size_t)2 * 194 * 194 * (512 + 64);     // 43,352,832
    size_t h_avail = ws_size / 2;
    int P = 50;
    {
        size_t n450 = 450 * per_patch_h; if (n450 < reg_h) n450 = reg_h;
        size_t n150 = 150 * per_patch_h; if (n150 < reg_h) n150 = reg_h;
        if (h_avail >= fixed_h + n450)      P = 450;
        else if (h_avail >= fixed_h + n150) P = 150;
    }
    const int nchunks = 450 / P;

    _Float16* P1 = ws + fixed_h;
    _Float16* D1 = P1 + (size_t)P * 676 * 128;
    _Float16* D2 = D1 + (size_t)P * 676 * 512;
    _Float16* A1 = ws + fixed_h;                                 // region reuse
    _Float16* A2 = A1 + (size_t)2 * 194 * 194 * 512;

    // ---- precompute fp16 operands ----
    ring_zero<<<(2 * 772 * 16 + 255) / 256, 256, 0, stream>>>(X16i, 2, 194, 128);
    build_x16i<<<4608, 256, 0, stream>>>(src, tgt, X16i);
    cvt_w<<<2304, 256, 0, stream>>>(W1,  W1h,  512, 128);
    cvt_w<<<4608, 256, 0, stream>>>(W2,  W2h,  256, 512);
    cvt_w<<<2304, 256, 0, stream>>>(Wr1, Wr1h, 512, 128);
    cvt_w<<<1152, 256, 0, stream>>>(Wr2, Wr2h, 64,  512);
    cvt_pad16<<<(16 * 9 * 256 + 255) / 256, 256, 0, stream>>>(W3,  W3p,  256);
    cvt_pad16<<<(16 * 9 * 64  + 255) / 256, 256, 0, stream>>>(Wr3, Wr3p, 64);

    // ---- attention path ----
    ring_zero<<<(P * 100 * 64 + 255) / 256, 256, 0, stream>>>(D1, P, 26, 512);
    ring_zero<<<(P * 100 * 32 + 255) / 256, 256, 0, stream>>>(D2, P, 26, 256);
    for (int c = 0; c < nchunks; ++c) {
        int p0 = c * P;
        g_patch<<<(P * 676 * 16 + 255) / 256, 256, 0, stream>>>(X16i, P1, p0, P);
        mfma_conv<4><<<swiz_grid(P, 8), 256, 0, stream>>>(P1, W1h, b1, D1, 128, 512, 26, 26, 0, P, 8);
        mfma_conv<4><<<swiz_grid(P, 4), 256, 0, stream>>>(D1, W2h, b2, D2, 512, 256, 26, 26, 0, P, 4);
        mfma_score<1, 1><<<P, 256, 0, stream>>>(D2, W3p, b3, score + (size_t)p0 * 576, 256, 26, P);
    }
    att_finalize<<<288, 256, 0, stream>>>(score, out + 73728);

    // ---- registration path ----
    if (P >= 150) {
        ring_zero<<<(2 * 772 * 64 + 255) / 256, 256, 0, stream>>>(A1, 2, 194, 512);
        ring_zero<<<(2 * 772 * 8  + 255) / 256, 256, 0, stream>>>(A2, 2, 194, 64);
        mfma_conv<4><<<swiz_grid(128, 8), 256, 0, stream>>>(X16i, Wr1h, br1, A1, 128, 512, 194, 194, 1, 128, 8);
        mfma_conv<2><<<swiz_grid(128, 2), 256, 0, stream>>>(A1, Wr2h, br2, A2, 512, 64, 194, 194, 1, 128, 2);
        mfma_score<2, 2><<<128, 256, 0, stream>>>(A2, Wr3p, br3, out, 64, 194, 128);
    } else {
        // small-workspace fallback: per batch, reuse chunk region
        _Float16* A1s = ws + fixed_h;
        _Float16* A2s = A1s + (size_t)194 * 194 * 512;
        for (int b = 0; b < 2; ++b) {
            ring_zero<<<(772 * 64 + 255) / 256, 256, 0, stream>>>(A1s, 1, 194, 512);
            ring_zero<<<(772 * 8  + 255) / 256, 256, 0, stream>>>(A2s, 1, 194, 64);
            mfma_conv<4><<<swiz_grid(64, 8), 256, 0, stream>>>(X16i + (size_t)b * 194 * 194 * 128,
                                                               Wr1h, br1, A1s, 128, 512, 194, 194, 1, 64, 8);
            mfma_conv<2><<<swiz_grid(64, 2), 256, 0, stream>>>(A1s, Wr2h, br2, A2s, 512, 64, 194, 194, 1, 64, 2);
            mfma_score<2, 2><<<64, 256, 0, stream>>>(A2s, Wr3p, br3, out + (size_t)b * 36864, 64, 194, 64);
        }
    }
}